// Round 4
// baseline (1333.582 us; speedup 1.0000x reference)
//
#include <hip/hip_runtime.h>
#include <hip/hip_fp16.h>
#include <hip/hip_cooperative_groups.h>

namespace cg = cooperative_groups;

// NLSPN deformable propagation, B=4, H=480, W=640, 18 steps.
// Round 4: persistent cooperative kernel, descriptors in registers.
//   - center sample (k=4) is exact: aref * fin[pix]  (no descriptor)
//   - 8 off-center samples: {clamped abs index, ak fp16 | wy u8 | wx u8},
//     boundary validity folded into (ak, wy, wx) -- exact transform.
//   - PXT=10 px/thread, 480 blocks, __launch_bounds__(256,2): capacity 512.
//   - runtime occupancy check + launch-rc check; fallbacks: PXT=20 @ 240
//     blocks (1 blk/CU), then a non-cooperative 18-launch descriptor path.

#define HH 480
#define WW 640
#define BB 4
#define HWSZ (HH * WW)        // 307200
#define NPIX (BB * HWSZ)      // 1228800
#define PROP_T 18
#define SLACK 704             // slack floats each side of state buffers
#define NTHR 256

struct f2u { float x, y; };   // 4-aligned pair load

__device__ __forceinline__ float fast_tanh(float x) {
    x = fminf(fmaxf(x, -15.0f), 15.0f);
    float e = __expf(2.0f * x);
    return __fdividef(e - 1.0f, e + 1.0f);
}

// Normalized affinities t[0..7] and aref for pixel gb (channel stride HWSZ).
__device__ __forceinline__ float affinities(const float* gb, float inv_scale,
                                            float t[8]) {
    float ssum = 1e-4f;
#pragma unroll
    for (int j = 0; j < 8; ++j) {
        float v = fast_tanh(gb[(16 + j) * HWSZ]) * inv_scale;
        t[j] = v; ssum += fabsf(v);
    }
    ssum = fmaxf(ssum, 1.0f);
    float rs = __fdividef(1.0f, ssum);
    float asum = 0.0f;
#pragma unroll
    for (int j = 0; j < 8; ++j) { t[j] *= rs; asum += t[j]; }
    return 1.0f - asum;
}

// Descriptor for sample k (k != 4) of pixel (b,y,x): clamped absolute index +
// packed {ak fp16 | wy u8 | wx u8} with boundary validity folded in (exact).
__device__ __forceinline__ void make_desc(int b, int y, int x, int k,
                                          float dy, float dx, float ak,
                                          int& idx_out, unsigned& w_out) {
    float py = (float)(y + k / 3 - 1) + dy;
    float px = (float)(x + k % 3 - 1) + dx;
    float y0f = floorf(py), x0f = floorf(px);
    float wy = py - y0f, wx = px - x0f;
    int y0 = (int)y0f, x0 = (int)x0f;
    // row -1 invalid -> only bottom row: ak*=wy, wy=1 ; row H-1 bottom invalid
    // -> only top row: ak*=(1-wy), wy=0 ; fully outside -> ak=0. Same for x.
    if (y0 == -1)                 { ak *= wy;        wy = 1.0f; }
    else if (y0 == HH - 1)        { ak *= 1.0f - wy; wy = 0.0f; }
    else if (y0 < -1 || y0 >= HH) { ak = 0.0f; }
    if (x0 == -1)                 { ak *= wx;        wx = 1.0f; }
    else if (x0 == WW - 1)        { ak *= 1.0f - wx; wx = 0.0f; }
    else if (x0 < -1 || x0 >= WW) { ak = 0.0f; }
    int yc = min(max(y0, -1), HH - 1);
    int xc = min(max(x0, -1), WW - 1);
    idx_out = b * HWSZ + yc * WW + xc;   // slack covers [-641, NPIX+641]
    unsigned uy = (unsigned)(int)(wy * 255.0f + 0.5f);
    unsigned ux = (unsigned)(int)(wx * 255.0f + 0.5f);
    w_out = ((unsigned)__half_as_ushort(__float2half(ak)) << 16)
          | (uy << 8) | ux;
}

__device__ __forceinline__ float sample_acc(const float* __restrict__ fin,
                                            int idx, unsigned u, float acc) {
    float ak = __half2float(__ushort_as_half((unsigned short)(u >> 16)));
    float wy = (float)((u >> 8) & 0xffu) * (1.0f / 255.0f);
    float wx = (float)(u & 0xffu) * (1.0f / 255.0f);
    const float* p = fin + idx;
    f2u r0 = *reinterpret_cast<const f2u*>(p);
    f2u r1 = *reinterpret_cast<const f2u*>(p + WW);
    float bot = ak * wy;
    float top = ak - bot;
    float omwx = 1.0f - wx;
    acc = fmaf(top * omwx, r0.x, acc);
    acc = fmaf(top * wx,   r0.y, acc);
    acc = fmaf(bot * omwx, r1.x, acc);
    acc = fmaf(bot * wx,   r1.y, acc);
    return acc;
}

// ---------------- persistent cooperative kernel ----------------
template <int PXT, int MINW>
__global__ __launch_bounds__(NTHR, MINW) void persist_kernel(
    const float* __restrict__ feat_init,
    const float* __restrict__ guid,
    const float* __restrict__ confidence,
    const float* __restrict__ feat_fix,
    const float* __restrict__ aff_scale,
    float* __restrict__ fA,
    float* __restrict__ fB,
    float* __restrict__ out)
{
    cg::grid_group grid = cg::this_grid();
    const int base = blockIdx.x * (NTHR * PXT) + threadIdx.x;

    int      idxd[PXT][8];
    unsigned wpk[PXT][8];
    unsigned pxc[PXT];        // aref fp16 <<16 | conf fp16
    float    ffp[PXT];        // m*feat_fix  (km = (ffp>0)?0:1, exact)

    const float inv_scale = __fdividef(1.0f, aff_scale[0] + 1e-8f);

    // phase 0: descriptors + state init
#pragma unroll
    for (int i = 0; i < PXT; ++i) {
        const int pix = base + i * NTHR;
        const int b = pix / HWSZ;
        const int q = pix - b * HWSZ;
        const int y = q / WW;
        const int x = q - y * WW;
        const float* gb = guid + (size_t)b * 24 * HWSZ + q;

        float ff = feat_fix[pix];
        float m  = (ff > 0.0f) ? 1.0f : 0.0f;
        float km = 1.0f - m;
        float conf = km * confidence[pix] + m;
        float f0   = km * feat_init[pix] + m * ff;
        fA[pix] = f0 * conf;
        ffp[i] = m * ff;

        float t[8];
        float aref = affinities(gb, inv_scale, t);
        pxc[i] = ((unsigned)__half_as_ushort(__float2half(aref)) << 16)
               | (unsigned)__half_as_ushort(__float2half(conf));

#pragma unroll
        for (int n = 0; n < 8; ++n) {
            const int k = (n < 4) ? n : (n + 1);
            float dy = gb[(2 * n) * HWSZ];
            float dx = gb[(2 * n + 1) * HWSZ];
            make_desc(b, y, x, k, dy, dx, t[n], idxd[i][n], wpk[i][n]);
        }
    }

    // 18 propagation steps
#pragma unroll 1
    for (int t = 0; t < PROP_T; ++t) {
        grid.sync();
        const float* fin = (t & 1) ? fB : fA;
        float* fout = (t == PROP_T - 1) ? out : ((t & 1) ? fA : fB);
#pragma unroll
        for (int i = 0; i < PXT; ++i) {
            const int pix = base + i * NTHR;
            unsigned pc = pxc[i];
            float aref = __half2float(__ushort_as_half((unsigned short)(pc >> 16)));
            float conf = __half2float(__ushort_as_half((unsigned short)(pc & 0xffffu)));
            float acc = aref * fin[pix];
#pragma unroll
            for (int n = 0; n < 8; ++n)
                acc = sample_acc(fin, idxd[i][n], wpk[i][n], acc);
            float km = (ffp[i] > 0.0f) ? 0.0f : 1.0f;
            float fnew = fmaf(km, acc, ffp[i]);     // f' = km*prop + m*ff
            fout[pix] = (t == PROP_T - 1) ? fnew : conf * fnew;
        }
    }
}

// ---------------- non-cooperative fallback ----------------
__global__ __launch_bounds__(NTHR) void precompute_kernel(
    const float* __restrict__ feat_init,
    const float* __restrict__ guid,
    const float* __restrict__ confidence,
    const float* __restrict__ feat_fix,
    const float* __restrict__ aff_scale,
    float* __restrict__ g0,
    float4* __restrict__ ac_mid,      // {A, C, aref, 0}
    float4* __restrict__ ac_last,
    int* __restrict__ idxArr,         // [8][NPIX]
    unsigned* __restrict__ wArr) {    // [8][NPIX]
    const int pix = blockIdx.x * NTHR + threadIdx.x;
    const int b = pix / HWSZ;
    const int q = pix - b * HWSZ;
    const int y = q / WW;
    const int x = q - y * WW;
    const float* gb = guid + (size_t)b * 24 * HWSZ + q;

    float ff = feat_fix[pix];
    float m  = (ff > 0.0f) ? 1.0f : 0.0f;
    float km = 1.0f - m;
    float conf = km * confidence[pix] + m;
    float f0   = km * feat_init[pix] + m * ff;
    g0[pix] = f0 * conf;

    const float inv_scale = __fdividef(1.0f, aff_scale[0] + 1e-8f);
    float t[8];
    float aref = affinities(gb, inv_scale, t);
    ac_mid[pix]  = make_float4(conf * km, conf * m * ff, aref, 0.0f);
    ac_last[pix] = make_float4(km, m * ff, aref, 0.0f);

#pragma unroll
    for (int n = 0; n < 8; ++n) {
        const int k = (n < 4) ? n : (n + 1);
        float dy = gb[(2 * n) * HWSZ];
        float dx = gb[(2 * n + 1) * HWSZ];
        int idx; unsigned w;
        make_desc(b, y, x, k, dy, dx, t[n], idx, w);
        idxArr[n * NPIX + pix] = idx;
        wArr[n * NPIX + pix] = w;
    }
}

__global__ __launch_bounds__(NTHR) void step_kernel(
    const float* __restrict__ fin,
    float* __restrict__ fout,
    const int* __restrict__ idxArr,
    const unsigned* __restrict__ wArr,
    const float4* __restrict__ ac) {
    const int pix = blockIdx.x * NTHR + threadIdx.x;
    float4 c = ac[pix];
    float acc = c.z * fin[pix];
#pragma unroll
    for (int n = 0; n < 8; ++n)
        acc = sample_acc(fin, idxArr[n * NPIX + pix], wArr[n * NPIX + pix], acc);
    fout[pix] = fmaf(c.x, acc, c.y);
}

extern "C" void kernel_launch(void* const* d_in, const int* in_sizes, int n_in,
                              void* d_out, int out_size, void* d_ws, size_t ws_size,
                              hipStream_t stream) {
    const float* feat_init  = (const float*)d_in[0];
    const float* guidance   = (const float*)d_in[1];
    const float* confidence = (const float*)d_in[2];
    const float* feat_fix   = (const float*)d_in[3];
    const float* aff_scale  = (const float*)d_in[4];

    const size_t bufFloats = (size_t)NPIX + 2 * SLACK;
    float* bufA = (float*)d_ws;
    float* bufB = bufA + bufFloats;
    float4* acMid  = (float4*)(bufB + bufFloats);
    float4* acLast = acMid + NPIX;
    int*      idxArr = (int*)(acLast + NPIX);
    unsigned* wArr   = (unsigned*)(idxArr + 8 * (size_t)NPIX);
    float* fA = bufA + SLACK;
    float* fB = bufB + SLACK;
    float* outp = (float*)d_out;

    // zero the slack strips (interiors are fully written before being read)
    hipMemsetAsync(bufA, 0, SLACK * sizeof(float), stream);
    hipMemsetAsync(bufA + SLACK + NPIX, 0, SLACK * sizeof(float), stream);
    hipMemsetAsync(bufB, 0, SLACK * sizeof(float), stream);
    hipMemsetAsync(bufB + SLACK + NPIX, 0, SLACK * sizeof(float), stream);

    void* args[] = {
        (void*)&feat_init, (void*)&guidance, (void*)&confidence,
        (void*)&feat_fix, (void*)&aff_scale,
        (void*)&fA, (void*)&fB, (void*)&outp
    };

    int dev = 0;
    hipGetDevice(&dev);
    int cu = 0;
    hipDeviceGetAttribute(&cu, hipDeviceAttributeMultiprocessorCount, dev);
    if (cu <= 0) cu = 256;

    // primary: PXT=10, 480 blocks, 2 blocks/CU guaranteed by launch bounds
    {
        const int nblk = NPIX / (NTHR * 10);   // 480
        int occ = 0;
        hipError_t qe = hipOccupancyMaxActiveBlocksPerMultiprocessor(
            &occ, reinterpret_cast<const void*>(&persist_kernel<10, 2>), NTHR, 0);
        if (qe == hipSuccess && occ * cu >= nblk) {
            hipError_t le = hipLaunchCooperativeKernel(
                reinterpret_cast<void*>(&persist_kernel<10, 2>),
                dim3(nblk), dim3(NTHR), args, 0, stream);
            if (le == hipSuccess) return;
        }
    }
    // secondary: PXT=20, 240 blocks, 1 block/CU
    {
        const int nblk = NPIX / (NTHR * 20);   // 240
        int occ = 0;
        hipError_t qe = hipOccupancyMaxActiveBlocksPerMultiprocessor(
            &occ, reinterpret_cast<const void*>(&persist_kernel<20, 1>), NTHR, 0);
        if (qe == hipSuccess && occ * cu >= nblk) {
            hipError_t le = hipLaunchCooperativeKernel(
                reinterpret_cast<void*>(&persist_kernel<20, 1>),
                dim3(nblk), dim3(NTHR), args, 0, stream);
            if (le == hipSuccess) return;
        }
    }
    // guaranteed fallback: descriptor build + 18 step launches
    precompute_kernel<<<NPIX / NTHR, NTHR, 0, stream>>>(
        feat_init, guidance, confidence, feat_fix, aff_scale,
        fA, acMid, acLast, idxArr, wArr);
    for (int t = 0; t < PROP_T; ++t) {
        const float* fin = (t & 1) ? fB : fA;
        float* fout = (t == PROP_T - 1) ? outp : ((t & 1) ? fA : fB);
        const float4* ac = (t == PROP_T - 1) ? acLast : acMid;
        step_kernel<<<NPIX / NTHR, NTHR, 0, stream>>>(fin, fout, idxArr, wArr, ac);
    }
}

// Round 5
// 647.976 us; speedup vs baseline: 2.0581x; 2.0581x over previous
//
#include <hip/hip_runtime.h>
#include <hip/hip_fp16.h>
#include <hip/hip_cooperative_groups.h>

namespace cg = cooperative_groups;

// NLSPN deformable propagation, B=4, H=480, W=640, 18 steps.
// Round 5: persistent cooperative kernel with COMPACT register descriptors.
//   sample desc = u32{rel i16 | wy u8 | wx u8} + fp16 ak  (6 B, 1.5 reg)
//   -> 14 regs/px, PXT=5 => 70 pinned regs, fits 128-VGPR cap (4 blk/CU).
// Descriptors built once by precompute_kernel (also feeds the non-coop
// fallback). Runtime guards: no-spill (localSizeBytes==0), occupancy>=grid,
// launch rc; otherwise 18-launch compact-streamed fallback.

#define HH 480
#define WW 640
#define BB 4
#define HWSZ (HH * WW)        // 307200
#define NPIX (BB * HWSZ)      // 1228800
#define PROP_T 18
#define SLACK 704             // slack floats each side of state buffers
#define NTHR 256
#define PXT 5
#define NBLK (NPIX / (NTHR * PXT))   // 960

struct f2u { float x, y; };   // 4-aligned pair load

__device__ __forceinline__ float fast_tanh(float x) {
    x = fminf(fmaxf(x, -15.0f), 15.0f);
    float e = __expf(2.0f * x);
    return __fdividef(e - 1.0f, e + 1.0f);
}

// Normalized affinities t[0..7] and aref (channel stride HWSZ).
__device__ __forceinline__ float affinities(const float* gb, float inv_scale,
                                            float t[8]) {
    float ssum = 1e-4f;
#pragma unroll
    for (int j = 0; j < 8; ++j) {
        float v = fast_tanh(gb[(16 + j) * HWSZ]) * inv_scale;
        t[j] = v; ssum += fabsf(v);
    }
    ssum = fmaxf(ssum, 1.0f);
    float rs = __fdividef(1.0f, ssum);
    float asum = 0.0f;
#pragma unroll
    for (int j = 0; j < 8; ++j) { t[j] *= rs; asum += t[j]; }
    return 1.0f - asum;
}

// Compact descriptor for sample k (k != 4) at pixel (y,x):
// pk = {rel i16 | wy u8 | wx u8}, akh = fp16(ak); boundary validity folded
// into (ak, wy, wx) exactly (R4-hardware-validated transform).
__device__ __forceinline__ void make_desc(int y, int x, int k,
                                          float dy, float dx, float ak,
                                          unsigned& pk, unsigned short& akh) {
    float py = (float)(y + k / 3 - 1) + dy;
    float px = (float)(x + k % 3 - 1) + dx;
    float y0f = floorf(py), x0f = floorf(px);
    float wy = py - y0f, wx = px - x0f;
    int y0 = (int)y0f, x0 = (int)x0f;
    if (y0 == -1)                 { ak *= wy;        wy = 1.0f; }
    else if (y0 == HH - 1)        { ak *= 1.0f - wy; wy = 0.0f; }
    else if (y0 < -1 || y0 >= HH) { ak = 0.0f; }
    if (x0 == -1)                 { ak *= wx;        wx = 1.0f; }
    else if (x0 == WW - 1)        { ak *= 1.0f - wx; wx = 0.0f; }
    else if (x0 < -1 || x0 >= WW) { ak = 0.0f; }
    int rel;
    if (ak == 0.0f) {
        rel = 0; wy = 0.0f; wx = 0.0f;
    } else {
        int yc = min(max(y0, -1), HH - 1);
        int xc = min(max(x0, -1), WW - 1);
        rel = (yc - y) * WW + (xc - x);          // |rel| <~ 4500 for N(0,1) offsets
        rel = min(max(rel, -32767), 32767);      // i16 safety (unreachable)
    }
    unsigned uy = (unsigned)(int)(wy * 255.0f + 0.5f);
    unsigned ux = (unsigned)(int)(wx * 255.0f + 0.5f);
    pk  = ((unsigned)(unsigned short)(short)rel << 16) | (uy << 8) | ux;
    akh = __half_as_ushort(__float2half(ak));
}

__device__ __forceinline__ float sample_rel(const float* __restrict__ fp,
                                            unsigned pk, unsigned short akh,
                                            float acc) {
    int rel = (int)(short)(pk >> 16);
    float wy = (float)((pk >> 8) & 0xffu) * (1.0f / 255.0f);
    float wx = (float)(pk & 0xffu) * (1.0f / 255.0f);
    float ak = __half2float(__ushort_as_half(akh));
    const float* p = fp + rel;
    f2u r0 = *reinterpret_cast<const f2u*>(p);
    f2u r1 = *reinterpret_cast<const f2u*>(p + WW);
    float bot = ak * wy;
    float top = ak - bot;
    float omwx = 1.0f - wx;
    acc = fmaf(top * omwx, r0.x, acc);
    acc = fmaf(top * wx,   r0.y, acc);
    acc = fmaf(bot * omwx, r1.x, acc);
    acc = fmaf(bot * wx,   r1.y, acc);
    return acc;
}

// ---------------- one-time descriptor build (feeds both paths) ----------------
__global__ __launch_bounds__(NTHR) void precompute_kernel(
    const float* __restrict__ feat_init,
    const float* __restrict__ guid,
    const float* __restrict__ confidence,
    const float* __restrict__ feat_fix,
    const float* __restrict__ aff_scale,
    float* __restrict__ g0,               // state init (interior base of bufA)
    unsigned* __restrict__ pk1Arr,        // [NPIX][8] px-major
    unsigned short* __restrict__ akArr,   // [NPIX][8] px-major
    unsigned* __restrict__ cfArr,         // {aref fp16 <<16 | conf fp16}
    float* __restrict__ ffpArr) {         // m*feat_fix
    const int pix = blockIdx.x * NTHR + threadIdx.x;
    const int b = pix / HWSZ;
    const int q = pix - b * HWSZ;
    const int y = q / WW;
    const int x = q - y * WW;
    const float* gb = guid + (size_t)b * 24 * HWSZ + q;

    float ff = feat_fix[pix];
    float m  = (ff > 0.0f) ? 1.0f : 0.0f;
    float km = 1.0f - m;
    float conf = km * confidence[pix] + m;
    float f0   = km * feat_init[pix] + m * ff;
    g0[pix] = f0 * conf;
    ffpArr[pix] = m * ff;

    const float inv_scale = __fdividef(1.0f, aff_scale[0] + 1e-8f);
    float t[8];
    float aref = affinities(gb, inv_scale, t);
    cfArr[pix] = ((unsigned)__half_as_ushort(__float2half(aref)) << 16)
               | (unsigned)__half_as_ushort(__float2half(conf));

    unsigned pk[8];
    unsigned short akh[8];
#pragma unroll
    for (int n = 0; n < 8; ++n) {
        const int k = (n < 4) ? n : (n + 1);
        float dy = gb[(2 * n) * HWSZ];
        float dx = gb[(2 * n + 1) * HWSZ];
        make_desc(y, x, k, dy, dx, t[n], pk[n], akh[n]);
    }
    uint4* pd = reinterpret_cast<uint4*>(pk1Arr) + 2 * pix;
    pd[0] = make_uint4(pk[0], pk[1], pk[2], pk[3]);
    pd[1] = make_uint4(pk[4], pk[5], pk[6], pk[7]);
    uint4 kv;
    kv.x = (unsigned)akh[0] | ((unsigned)akh[1] << 16);
    kv.y = (unsigned)akh[2] | ((unsigned)akh[3] << 16);
    kv.z = (unsigned)akh[4] | ((unsigned)akh[5] << 16);
    kv.w = (unsigned)akh[6] | ((unsigned)akh[7] << 16);
    reinterpret_cast<uint4*>(akArr)[pix] = kv;
}

// ---------------- persistent cooperative kernel ----------------
__global__ __launch_bounds__(NTHR, 4) void persist_kernel(
    const unsigned* __restrict__ pk1Arr,
    const unsigned short* __restrict__ akArr,
    const unsigned* __restrict__ cfArr,
    const float* __restrict__ ffpArr,
    float* __restrict__ fA,
    float* __restrict__ fB,
    float* __restrict__ out)
{
    cg::grid_group grid = cg::this_grid();
    const int base = blockIdx.x * (NTHR * PXT) + threadIdx.x;

    uint4 pka[PXT], pkb[PXT], akv[PXT];   // 12 regs/px
    unsigned cfr[PXT];                    // 1 reg/px
    float    ffr[PXT];                    // 1 reg/px

#pragma unroll
    for (int i = 0; i < PXT; ++i) {
        const int pix = base + i * NTHR;
        const uint4* pd = reinterpret_cast<const uint4*>(pk1Arr) + 2 * pix;
        pka[i] = pd[0];
        pkb[i] = pd[1];
        akv[i] = reinterpret_cast<const uint4*>(akArr)[pix];
        cfr[i] = cfArr[pix];
        ffr[i] = ffpArr[pix];
    }

#pragma unroll 1
    for (int t = 0; t < PROP_T; ++t) {
        grid.sync();
        const float* fin = (t & 1) ? fB : fA;
        float* fout = (t == PROP_T - 1) ? out : ((t & 1) ? fA : fB);
        const bool last = (t == PROP_T - 1);
#pragma unroll
        for (int i = 0; i < PXT; ++i) {
            const int pix = base + i * NTHR;
            const float* fp = fin + pix;
            unsigned c = cfr[i];
            float aref = __half2float(__ushort_as_half((unsigned short)(c >> 16)));
            float conf = __half2float(__ushort_as_half((unsigned short)(c & 0xffffu)));
            float acc = aref * fp[0];
            uint4 A = pka[i], B = pkb[i], K = akv[i];
            acc = sample_rel(fp, A.x, (unsigned short)(K.x & 0xffffu), acc);
            acc = sample_rel(fp, A.y, (unsigned short)(K.x >> 16),     acc);
            acc = sample_rel(fp, A.z, (unsigned short)(K.y & 0xffffu), acc);
            acc = sample_rel(fp, A.w, (unsigned short)(K.y >> 16),     acc);
            acc = sample_rel(fp, B.x, (unsigned short)(K.z & 0xffffu), acc);
            acc = sample_rel(fp, B.y, (unsigned short)(K.z >> 16),     acc);
            acc = sample_rel(fp, B.z, (unsigned short)(K.w & 0xffffu), acc);
            acc = sample_rel(fp, B.w, (unsigned short)(K.w >> 16),     acc);
            float km = (ffr[i] > 0.0f) ? 0.0f : 1.0f;
            float fnew = fmaf(km, acc, ffr[i]);     // f' = km*prop + m*ff
            fout[pix] = last ? fnew : conf * fnew;  // g' = f'*conf
        }
    }
}

// ---------------- non-cooperative fallback (compact streamed) ----------------
__global__ __launch_bounds__(NTHR) void step_kernel(
    const float* __restrict__ fin,
    float* __restrict__ fout,
    const unsigned* __restrict__ pk1Arr,
    const unsigned short* __restrict__ akArr,
    const unsigned* __restrict__ cfArr,
    const float* __restrict__ ffpArr,
    int last) {
    const int pix = blockIdx.x * NTHR + threadIdx.x;
    const float* fp = fin + pix;
    const uint4* pd = reinterpret_cast<const uint4*>(pk1Arr) + 2 * pix;
    uint4 A = pd[0], B = pd[1];
    uint4 K = reinterpret_cast<const uint4*>(akArr)[pix];
    unsigned c = cfArr[pix];
    float ffv = ffpArr[pix];
    float aref = __half2float(__ushort_as_half((unsigned short)(c >> 16)));
    float conf = __half2float(__ushort_as_half((unsigned short)(c & 0xffffu)));
    float acc = aref * fp[0];
    acc = sample_rel(fp, A.x, (unsigned short)(K.x & 0xffffu), acc);
    acc = sample_rel(fp, A.y, (unsigned short)(K.x >> 16),     acc);
    acc = sample_rel(fp, A.z, (unsigned short)(K.y & 0xffffu), acc);
    acc = sample_rel(fp, A.w, (unsigned short)(K.y >> 16),     acc);
    acc = sample_rel(fp, B.x, (unsigned short)(K.z & 0xffffu), acc);
    acc = sample_rel(fp, B.y, (unsigned short)(K.z >> 16),     acc);
    acc = sample_rel(fp, B.z, (unsigned short)(K.w & 0xffffu), acc);
    acc = sample_rel(fp, B.w, (unsigned short)(K.w >> 16),     acc);
    float km = (ffv > 0.0f) ? 0.0f : 1.0f;
    float fnew = fmaf(km, acc, ffv);
    fout[pix] = last ? fnew : conf * fnew;
}

extern "C" void kernel_launch(void* const* d_in, const int* in_sizes, int n_in,
                              void* d_out, int out_size, void* d_ws, size_t ws_size,
                              hipStream_t stream) {
    const float* feat_init  = (const float*)d_in[0];
    const float* guidance   = (const float*)d_in[1];
    const float* confidence = (const float*)d_in[2];
    const float* feat_fix   = (const float*)d_in[3];
    const float* aff_scale  = (const float*)d_in[4];

    // ws layout (16B-aligned sections): bufA | bufB | pk1 | ak | cf | ffp  (~89 MB)
    const size_t bufFloats = (size_t)NPIX + 2 * SLACK;      // x4 bytes, 16B-divisible
    float* bufA = (float*)d_ws;
    float* bufB = bufA + bufFloats;
    unsigned* pk1Arr = (unsigned*)(bufB + bufFloats);        // NPIX*8 u32
    unsigned short* akArr = (unsigned short*)(pk1Arr + 8 * (size_t)NPIX);  // NPIX*8 u16
    unsigned* cfArr = (unsigned*)(akArr + 8 * (size_t)NPIX); // NPIX u32
    float* ffpArr = (float*)(cfArr + NPIX);                  // NPIX f32
    float* fA = bufA + SLACK;
    float* fB = bufB + SLACK;
    float* outp = (float*)d_out;

    // zero the slack strips (interiors fully written before read)
    hipMemsetAsync(bufA, 0, SLACK * sizeof(float), stream);
    hipMemsetAsync(bufA + SLACK + NPIX, 0, SLACK * sizeof(float), stream);
    hipMemsetAsync(bufB, 0, SLACK * sizeof(float), stream);
    hipMemsetAsync(bufB + SLACK + NPIX, 0, SLACK * sizeof(float), stream);

    precompute_kernel<<<NPIX / NTHR, NTHR, 0, stream>>>(
        feat_init, guidance, confidence, feat_fix, aff_scale,
        fA, pk1Arr, akArr, cfArr, ffpArr);

    // ---- primary: persistent cooperative kernel, guarded ----
    bool tryCoop = false;
    {
        hipFuncAttributes fa{};
        if (hipFuncGetAttributes(&fa, reinterpret_cast<const void*>(persist_kernel))
                == hipSuccess && fa.localSizeBytes == 0) {
            int occ = 0;
            if (hipOccupancyMaxActiveBlocksPerMultiprocessor(
                    &occ, reinterpret_cast<const void*>(persist_kernel), NTHR, 0)
                    == hipSuccess) {
                int dev = 0, cu = 0;
                hipGetDevice(&dev);
                hipDeviceGetAttribute(&cu, hipDeviceAttributeMultiprocessorCount, dev);
                if ((long)occ * cu >= NBLK) tryCoop = true;
            }
        }
    }
    if (tryCoop) {
        void* args[] = { (void*)&pk1Arr, (void*)&akArr, (void*)&cfArr,
                         (void*)&ffpArr, (void*)&fA, (void*)&fB, (void*)&outp };
        if (hipLaunchCooperativeKernel(reinterpret_cast<void*>(persist_kernel),
                                       dim3(NBLK), dim3(NTHR), args, 0, stream)
                == hipSuccess)
            return;
    }

    // ---- fallback: 18 compact-streamed launches ----
    for (int t = 0; t < PROP_T; ++t) {
        const float* fin = (t & 1) ? fB : fA;
        float* fout = (t == PROP_T - 1) ? outp : ((t & 1) ? fA : fB);
        step_kernel<<<NPIX / NTHR, NTHR, 0, stream>>>(
            fin, fout, pk1Arr, akArr, cfArr, ffpArr, (t == PROP_T - 1) ? 1 : 0);
    }
}